// Round 3
// baseline (241.655 us; speedup 1.0000x reference)
//
#include <hip/hip_runtime.h>

// SparseMHA, fixed out-degree CSR graph attention.
// ALL inputs/outputs are fp32 (per the reference — round-1/2 NaN was caused by
// reading fp32 buffers as bf16; garbage exponents -> Inf -> NaN in softmax).
//
// Phase 1: QKV projections. h and W are split into bf16 hi+lo on the fly;
//          3 MFMAs (ah*bh + ah*bl + al*bh) give ~fp32-accurate results, which
//          are rounded ONCE to bf16 for storage. q (pre-scaled by 0.25) is
//          embedded in the first 256 B of each row's 512 B output slot
//          (read + overwritten only by that row's own wave -> race-free);
//          k, v go to d_ws (25.6 MB).
// Phase 2: one wave per row. Scores via mfma_16x16x32_bf16 with gathered K
//          rows as A and diagonal-expanded q as B; softmax via 2 shfl_xor;
//          PV as a coalesced per-lane fp32 loop; fp32 float2 stores.

typedef unsigned short ushort_t;
typedef unsigned int uint32;
typedef short short8 __attribute__((ext_vector_type(8)));
typedef float f32x4 __attribute__((ext_vector_type(4)));

#define HID 128
#define DEG 16

__device__ __forceinline__ float bf2f(ushort_t u) {
  uint32 x = ((uint32)u) << 16;
  return __builtin_bit_cast(float, x);
}
__device__ __forceinline__ ushort_t f2bf(float f) {
  uint32 u = __builtin_bit_cast(uint32, f);
  u += 0x7fffu + ((u >> 16) & 1u);   // round-to-nearest-even
  return (ushort_t)(u >> 16);
}

// Split 8 consecutive fp32 into bf16 hi + lo fragments (hi = RNE(x), lo = RNE(x - hi)).
__device__ __forceinline__ void split8(const float* __restrict__ p, short8& hi, short8& lo) {
#pragma unroll
  for (int j = 0; j < 8; j++) {
    float x = p[j];
    ushort_t hb = f2bf(x);
    hi[j] = (short)hb;
    lo[j] = (short)f2bf(x - bf2f(hb));
  }
}

// ---------------- Phase 1: Q/K/V projection GEMMs ----------------
// out[i,c] = sum_k h[i,k] * W[c,k] + b[c]  (ref: h @ W.T, W row-major [c][k]).
// blockIdx.y selects {q,k,v}; q scaled by head_dim^-0.5 = 0.25 (after bias).
// Block = 256 threads (4 waves); each wave computes 16 rows x 128 cols.
__global__ __launch_bounds__(256) void qkv_kernel(
    const float* __restrict__ h,
    const float* __restrict__ Wq, const float* __restrict__ bq,
    const float* __restrict__ Wk, const float* __restrict__ bk,
    const float* __restrict__ Wv, const float* __restrict__ bv,
    ushort_t* __restrict__ qs, ushort_t* __restrict__ ks, ushort_t* __restrict__ vs,
    int n) {
  const int which = blockIdx.y;
  const float* __restrict__ W = (which == 0) ? Wq : (which == 1) ? Wk : Wv;
  const float* __restrict__ bias = (which == 0) ? bq : (which == 1) ? bk : bv;
  ushort_t* __restrict__ outp = (which == 0) ? qs : (which == 1) ? ks : vs;
  const int ostride = (which == 0) ? 256 : 128;  // q rows are 256-ushort apart (inside fp32 out rows)
  const float scale = (which == 0) ? 0.25f : 1.0f;

  const int wave = threadIdx.x >> 6;
  const int l = threadIdx.x & 63;
  const int lm = l & 15;     // A-row / B-col index within tile
  const int lq = l >> 4;     // quad
  const int m0 = blockIdx.x * 64 + wave * 16;

  const int arow = m0 + lm;
  const int arow_c = (arow < n) ? arow : (n - 1);  // clamp ragged last block
  const float* aptr = h + (size_t)arow_c * HID + lq * 8;

  f32x4 acc[8];
#pragma unroll
  for (int t = 0; t < 8; t++) acc[t] = (f32x4){0.f, 0.f, 0.f, 0.f};

#pragma unroll
  for (int kt = 0; kt < 4; kt++) {
    short8 ah, al;
    split8(aptr + kt * 32, ah, al);
#pragma unroll
    for (int t = 0; t < 8; t++) {
      short8 bh, bl;
      split8(W + (size_t)(t * 16 + lm) * HID + kt * 32 + lq * 8, bh, bl);
      acc[t] = __builtin_amdgcn_mfma_f32_16x16x32_bf16(ah, bh, acc[t], 0, 0, 0);
      acc[t] = __builtin_amdgcn_mfma_f32_16x16x32_bf16(ah, bl, acc[t], 0, 0, 0);
      acc[t] = __builtin_amdgcn_mfma_f32_16x16x32_bf16(al, bh, acc[t], 0, 0, 0);
    }
  }

  // Epilogue: D[m][c] with c = lm (col), m = lq*4 + r (row).
#pragma unroll
  for (int t = 0; t < 8; t++) {
    const int col = t * 16 + lm;
    const float bv_ = bias[col];
#pragma unroll
    for (int r = 0; r < 4; r++) {
      const int row = m0 + lq * 4 + r;
      if (row < n) {
        outp[(size_t)row * ostride + col] = f2bf((acc[t][r] + bv_) * scale);
      }
    }
  }
}

// ---------------- Phase 2: fused scores + softmax + aggregate ----------------
// One wave per row (4 rows / 256-thread block).
// Scores: D[e][h] = sum_k K[c_e][k] * Bq[k][h], Bq[k][h] = q[k] iff k%8==h.
// A layout: A[m=lane&15][k=quad*8+j]; B: B[k=quad*8+j][n=lane&15];
// C/D: col=lane&15 (head), row=quad*4+reg (edge).
__global__ __launch_bounds__(256) void attn_kernel(
    const int* __restrict__ col_ind,
    const ushort_t* __restrict__ qs, const ushort_t* __restrict__ ks,
    const ushort_t* __restrict__ vs, float* __restrict__ out, int n) {
  __shared__ __align__(16) float lds_attn[4 * DEG * 8];  // [wave][edge][head]

  const int wv = threadIdx.x >> 6;
  const int l = threadIdx.x & 63;
  const int lm = l & 15;
  const int lq = l >> 4;

  int row = blockIdx.x * 4 + wv;
  const bool valid = (row < n);
  if (!valid) row = n - 1;  // clamp; no early return (keep __syncthreads safe)
  const int eb = row * DEG;

  // --- scores via MFMA ---
  const int cm = col_ind[eb + lm];                 // this lane's A-operand edge
  const ushort_t* kp = ks + (size_t)cm * HID + lq * 8;
  const ushort_t* qp = qs + (size_t)row * 256;     // q embedded in out row

  f32x4 acc = (f32x4){0.f, 0.f, 0.f, 0.f};
#pragma unroll
  for (int kt = 0; kt < 4; kt++) {
    short8 af = *(const short8*)(kp + kt * 32);
    ushort_t qv = (lm < 8) ? qp[kt * 32 + lq * 8 + lm] : (ushort_t)0;
    short8 bf;
#pragma unroll
    for (int j = 0; j < 8; j++) bf[j] = (lm == j) ? (short)qv : (short)0;
    acc = __builtin_amdgcn_mfma_f32_16x16x32_bf16(af, bf, acc, 0, 0, 0);
  }
  // acc[r] = score[edge = lq*4 + r][head = lm]   (lm < 8 valid)

  // --- segment softmax over the 16 edges (per head) ---
  float m = fmaxf(fmaxf(acc[0], acc[1]), fmaxf(acc[2], acc[3]));
  m = fmaxf(m, __shfl_xor(m, 16, 64));
  m = fmaxf(m, __shfl_xor(m, 32, 64));
  float e0 = __expf(acc[0] - m), e1 = __expf(acc[1] - m);
  float e2 = __expf(acc[2] - m), e3 = __expf(acc[3] - m);
  float s = e0 + e1 + e2 + e3;
  s += __shfl_xor(s, 16, 64);
  s += __shfl_xor(s, 32, 64);
  const float inv = 1.0f / s;

  if (lm < 8) {
    float* ap = &lds_attn[wv * (DEG * 8)];
    ap[(lq * 4 + 0) * 8 + lm] = e0 * inv;
    ap[(lq * 4 + 1) * 8 + lm] = e1 * inv;
    ap[(lq * 4 + 2) * 8 + lm] = e2 * inv;
    ap[(lq * 4 + 3) * 8 + lm] = e3 * inv;
  }
  __syncthreads();

  // --- PV aggregation: lane handles output elements 2l, 2l+1 ---
  const float* ap = &lds_attn[wv * (DEG * 8)];
  const int h0 = 2 * (l & 3);  // head of element 2l; element 2l+1 is head h0+1
  float o0 = 0.f, o1 = 0.f;
#pragma unroll
  for (int e = 0; e < DEG; e++) {
    const int c = col_ind[eb + e];
    const uint32 vbits = *(const uint32*)(vs + (size_t)c * HID + 2 * l);
    const float2 at = *(const float2*)(ap + e * 8 + h0);
    o0 += at.x * bf2f((ushort_t)(vbits & 0xffffu));
    o1 += at.y * bf2f((ushort_t)(vbits >> 16));
  }

  // Overwrites this row's out slot (incl. the embedded q, already consumed —
  // the store's data depends on the q loads, so ordering is by dataflow).
  if (valid) {
    float2 o = {o0, o1};
    *(float2*)(out + (size_t)row * HID + 2 * l) = o;
  }
}

extern "C" void kernel_launch(void* const* d_in, const int* in_sizes, int n_in,
                              void* d_out, int out_size, void* d_ws, size_t ws_size,
                              hipStream_t stream) {
  const float* h  = (const float*)d_in[0];
  const float* Wq = (const float*)d_in[1];
  const float* bq = (const float*)d_in[2];
  const float* Wk = (const float*)d_in[3];
  const float* bk = (const float*)d_in[4];
  const float* Wv = (const float*)d_in[5];
  const float* bv = (const float*)d_in[6];
  // d_in[7] = row_ptr (fixed-degree: row i edges = [i*16, i*16+16)) — unused
  const int* col_ind = (const int*)d_in[8];
  // d_in[9] = num_heads (= 8) — hardcoded in the layout math

  const int n = in_sizes[0] / HID;  // 50000

  // q (bf16) lives in the first 256 B of each 512 B fp32 out row; k,v in d_ws.
  ushort_t* qs = (ushort_t*)d_out;
  ushort_t* ks = (ushort_t*)d_ws;
  ushort_t* vs = ks + (size_t)n * HID;
  float* outf = (float*)d_out;

  dim3 g1((n + 63) / 64, 3);
  qkv_kernel<<<g1, 256, 0, stream>>>(h, Wq, bq, Wk, bk, Wv, bv, qs, ks, vs, n);

  attn_kernel<<<(n + 3) / 4, 256, 0, stream>>>(col_ind, qs, ks, vs, outf, n);
}

// Round 5
// 217.082 us; speedup vs baseline: 1.1132x; 1.1132x over previous
//
#include <hip/hip_runtime.h>
#include <hip/hip_bf16.h>

// SparseMHA, fixed out-degree CSR graph attention. fp32 in/out.
// r3 -> r5: qkv was issue-bound on in-loop fp32->bf16 hi/lo splitting of the
// B tile (2560 VALU insts/wave, MfmaUtil 5%). Now W is pre-split ONCE by a
// tiny prep kernel; qkv splits only its A rows (packed cvt) and runs 32
// rows/wave. attn: V prefetched into registers before softmax, block barrier
// replaced by wave-local LDS ordering (per-wave private LDS region).
// (r4 fix: bit_cast of __hip_bfloat162 -> __builtin_memcpy.)

typedef unsigned short ushort_t;
typedef unsigned int uint32;
typedef short short8 __attribute__((ext_vector_type(8)));
typedef float f32x4 __attribute__((ext_vector_type(4)));

#define HID 128
#define DEG 16

__device__ __forceinline__ float bf2f(ushort_t u) {
  uint32 x = ((uint32)u) << 16;
  return __builtin_bit_cast(float, x);
}
__device__ __forceinline__ ushort_t f2bf(float f) {
  uint32 u = __builtin_bit_cast(uint32, f);
  u += 0x7fffu + ((u >> 16) & 1u);   // RNE
  return (ushort_t)(u >> 16);
}

// Packed split of 2 fp32 -> packed bf16 hi pair + lo pair (RNE, v_cvt_pk path).
__device__ __forceinline__ void split2(float x, float y, uint32& hi, uint32& lo) {
  __hip_bfloat162 h2 = __float22bfloat162_rn(float2{x, y});
  __builtin_memcpy(&hi, &h2, 4);
  float hx = __builtin_bit_cast(float, hi << 16);
  float hy = __builtin_bit_cast(float, hi & 0xffff0000u);
  __hip_bfloat162 l2 = __float22bfloat162_rn(float2{x - hx, y - hy});
  __builtin_memcpy(&lo, &l2, 4);
}

// 8 consecutive fp32 (32B-aligned) -> short8 hi + short8 lo.
__device__ __forceinline__ void split8p(const float* __restrict__ p, short8& hi, short8& lo) {
  float4 a = *(const float4*)p;
  float4 b = *(const float4*)(p + 4);
  uint32* hu = (uint32*)&hi;
  uint32* lu = (uint32*)&lo;
  split2(a.x, a.y, hu[0], lu[0]);
  split2(a.z, a.w, hu[1], lu[1]);
  split2(b.x, b.y, hu[2], lu[2]);
  split2(b.z, b.w, hu[3], lu[3]);
}

// ---------------- Phase 0: pre-split Wq|Wk|Wv into bf16 hi/lo ----------------
// 3 x 16384 elems; 24 blocks x 256 threads x 8 elems. Row-major layout kept.
__global__ __launch_bounds__(256) void prep_kernel(
    const float* __restrict__ Wq, const float* __restrict__ Wk,
    const float* __restrict__ Wv,
    ushort_t* __restrict__ whi, ushort_t* __restrict__ wlo) {
  const int idx8 = (blockIdx.x * 256 + threadIdx.x) * 8;   // [0, 49152)
  const float* W = (idx8 < 16384) ? Wq : (idx8 < 32768) ? Wk : Wv;
  const int off = idx8 & 16383;
  short8 hi, lo;
  split8p(W + off, hi, lo);
  *(short8*)(whi + idx8) = hi;
  *(short8*)(wlo + idx8) = lo;
}

// ---------------- Phase 1: Q/K/V projection GEMMs ----------------
// out[i,c] = sum_k h[i,k]*W[c,k] + b[c]; q scaled by 0.25 after bias.
// Grid (ceil(n/128), 3); block 256 = 4 waves; wave computes 32 rows x 128 cols
// (two 16-row A fragments), 3 MFMAs per tile (ah*bh + ah*bl + al*bh).
__global__ __launch_bounds__(256) void qkv_kernel(
    const float* __restrict__ h,
    const float* __restrict__ bq, const float* __restrict__ bk,
    const float* __restrict__ bv,
    const ushort_t* __restrict__ whi, const ushort_t* __restrict__ wlo,
    ushort_t* __restrict__ qs, ushort_t* __restrict__ ks, ushort_t* __restrict__ vs,
    int n) {
  const int which = blockIdx.y;
  const float* __restrict__ bias = (which == 0) ? bq : (which == 1) ? bk : bv;
  ushort_t* __restrict__ outp = (which == 0) ? qs : (which == 1) ? ks : vs;
  const int ostride = (which == 0) ? 256 : 128;  // q rows live inside 512B fp32 out rows
  const float scale = (which == 0) ? 0.25f : 1.0f;
  const ushort_t* __restrict__ Wh = whi + which * 16384;
  const ushort_t* __restrict__ Wl = wlo + which * 16384;

  const int wave = threadIdx.x >> 6;
  const int l = threadIdx.x & 63;
  const int lm = l & 15;
  const int lq = l >> 4;
  const int m0 = blockIdx.x * 128 + wave * 32;

  int ar0 = m0 + lm;        if (ar0 >= n) ar0 = n - 1;
  int ar1 = m0 + 16 + lm;   if (ar1 >= n) ar1 = n - 1;
  const float* ap0 = h + (size_t)ar0 * HID + lq * 8;
  const float* ap1 = h + (size_t)ar1 * HID + lq * 8;

  f32x4 acc[2][8];
#pragma unroll
  for (int f = 0; f < 2; f++)
#pragma unroll
    for (int t = 0; t < 8; t++) acc[f][t] = (f32x4){0.f, 0.f, 0.f, 0.f};

#pragma unroll
  for (int kt = 0; kt < 4; kt++) {
    short8 ah0, al0, ah1, al1;
    split8p(ap0 + kt * 32, ah0, al0);
    split8p(ap1 + kt * 32, ah1, al1);
    const int boff = kt * 32 + lq * 8 + lm * HID;
#pragma unroll
    for (int t = 0; t < 8; t++) {
      short8 bh = *(const short8*)(Wh + t * 16 * HID + boff);
      short8 bl = *(const short8*)(Wl + t * 16 * HID + boff);
      acc[0][t] = __builtin_amdgcn_mfma_f32_16x16x32_bf16(ah0, bh, acc[0][t], 0, 0, 0);
      acc[0][t] = __builtin_amdgcn_mfma_f32_16x16x32_bf16(ah0, bl, acc[0][t], 0, 0, 0);
      acc[0][t] = __builtin_amdgcn_mfma_f32_16x16x32_bf16(al0, bh, acc[0][t], 0, 0, 0);
      acc[1][t] = __builtin_amdgcn_mfma_f32_16x16x32_bf16(ah1, bh, acc[1][t], 0, 0, 0);
      acc[1][t] = __builtin_amdgcn_mfma_f32_16x16x32_bf16(ah1, bl, acc[1][t], 0, 0, 0);
      acc[1][t] = __builtin_amdgcn_mfma_f32_16x16x32_bf16(al1, bh, acc[1][t], 0, 0, 0);
    }
  }

  // Epilogue: D[m][c], c = lm, m = f*16 + lq*4 + r.
#pragma unroll
  for (int t = 0; t < 8; t++) {
    const int col = t * 16 + lm;
    const float bv_ = bias[col];
#pragma unroll
    for (int f = 0; f < 2; f++) {
#pragma unroll
      for (int r = 0; r < 4; r++) {
        const int row = m0 + f * 16 + lq * 4 + r;
        if (row < n) outp[(size_t)row * ostride + col] = f2bf((acc[f][t][r] + bv_) * scale);
      }
    }
  }
}

// ---------------- Phase 2: fused scores + softmax + aggregate ----------------
// One wave per row. Scores via MFMA (gathered K rows as A, diagonal-expanded q
// as B). V prefetched into registers BEFORE softmax (independent), so the wave
// has one memory round, not two. LDS region is per-wave private -> no block
// barrier; DS ops are in-order per wave, lgkmcnt(0) as insurance.
__global__ __launch_bounds__(256) void attn_kernel(
    const int* __restrict__ col_ind,
    const ushort_t* __restrict__ qs, const ushort_t* __restrict__ ks,
    const ushort_t* __restrict__ vs, float* __restrict__ out, int n) {
  __shared__ __align__(16) float lds_attn[4 * DEG * 8];  // [wave][edge][head]

  const int wv = threadIdx.x >> 6;
  const int l = threadIdx.x & 63;
  const int lm = l & 15;
  const int lq = l >> 4;

  int row = blockIdx.x * 4 + wv;
  if (row >= n) row = n - 1;  // n % 4 == 0 for the bench shape; safety clamp
  const int eb = row * DEG;

  const int cm = col_ind[eb + lm];                 // this lane's A-operand edge
  const ushort_t* kp = ks + (size_t)cm * HID + lq * 8;
  const ushort_t* qp = qs + (size_t)row * 256;     // q embedded in out row

  // Issue K-fragment + q loads.
  short8 af[4];
  ushort_t qv[4];
#pragma unroll
  for (int kt = 0; kt < 4; kt++) {
    af[kt] = *(const short8*)(kp + kt * 32);
    qv[kt] = (lm < 8) ? qp[kt * 32 + lq * 8 + lm] : (ushort_t)0;
  }

  // Prefetch all V words (independent of scores; hides behind MFMA+softmax).
  uint32 vreg[DEG];
#pragma unroll
  for (int e = 0; e < DEG; e++) {
    const int c = col_ind[eb + e];                 // wave-uniform -> s_load
    vreg[e] = *(const uint32*)(vs + (size_t)c * HID + 2 * l);
  }

  f32x4 acc = (f32x4){0.f, 0.f, 0.f, 0.f};
#pragma unroll
  for (int kt = 0; kt < 4; kt++) {
    short8 bf;
#pragma unroll
    for (int j = 0; j < 8; j++) bf[j] = (lm == j) ? (short)qv[kt] : (short)0;
    acc = __builtin_amdgcn_mfma_f32_16x16x32_bf16(af[kt], bf, acc, 0, 0, 0);
  }
  // acc[r] = score[edge = lq*4 + r][head = lm]   (lm < 8 valid)

  // Segment softmax over 16 edges, per head (lanes sharing lm).
  float m = fmaxf(fmaxf(acc[0], acc[1]), fmaxf(acc[2], acc[3]));
  m = fmaxf(m, __shfl_xor(m, 16, 64));
  m = fmaxf(m, __shfl_xor(m, 32, 64));
  float e0 = __expf(acc[0] - m), e1 = __expf(acc[1] - m);
  float e2 = __expf(acc[2] - m), e3 = __expf(acc[3] - m);
  float s = e0 + e1 + e2 + e3;
  s += __shfl_xor(s, 16, 64);
  s += __shfl_xor(s, 32, 64);
  const float inv = 1.0f / s;

  float* ap = &lds_attn[wv * (DEG * 8)];
  if (lm < 8) {
    ap[(lq * 4 + 0) * 8 + lm] = e0 * inv;
    ap[(lq * 4 + 1) * 8 + lm] = e1 * inv;
    ap[(lq * 4 + 2) * 8 + lm] = e2 * inv;
    ap[(lq * 4 + 3) * 8 + lm] = e3 * inv;
  }
  // Wave-local LDS ordering (region private to this wave; DS in-order per wave).
  asm volatile("s_waitcnt lgkmcnt(0)" ::: "memory");
  __builtin_amdgcn_wave_barrier();

  // PV: lane covers output elements 2l, 2l+1 (heads h0, h0+1).
  const int h0 = 2 * (l & 3);
  float o0 = 0.f, o1 = 0.f;
#pragma unroll
  for (int e = 0; e < DEG; e++) {
    const float2 at = *(const float2*)(ap + e * 8 + h0);
    o0 += at.x * bf2f((ushort_t)(vreg[e] & 0xffffu));
    o1 += at.y * bf2f((ushort_t)(vreg[e] >> 16));
  }

  float2 o = {o0, o1};
  *(float2*)(out + (size_t)row * HID + 2 * l) = o;  // overwrites consumed q slot
}

extern "C" void kernel_launch(void* const* d_in, const int* in_sizes, int n_in,
                              void* d_out, int out_size, void* d_ws, size_t ws_size,
                              hipStream_t stream) {
  const float* h  = (const float*)d_in[0];
  const float* Wq = (const float*)d_in[1];
  const float* bq = (const float*)d_in[2];
  const float* Wk = (const float*)d_in[3];
  const float* bk = (const float*)d_in[4];
  const float* Wv = (const float*)d_in[5];
  const float* bv = (const float*)d_in[6];
  // d_in[7] = row_ptr (fixed degree 16) — unused
  const int* col_ind = (const int*)d_in[8];
  // d_in[9] = num_heads (= 8) — hardcoded in layout math

  const int n = in_sizes[0] / HID;  // 50000

  // ws layout (≈25.8 MB): k, v bf16 tables + W hi/lo splits. q (bf16) lives in
  // the first 256 B of each row's 512 B fp32 out slot (consumed by its own
  // wave before being overwritten).
  ushort_t* ks  = (ushort_t*)d_ws;
  ushort_t* vs  = ks + (size_t)n * HID;
  ushort_t* whi = vs + (size_t)n * HID;
  ushort_t* wlo = whi + 3 * 16384;
  ushort_t* qs  = (ushort_t*)d_out;
  float* outf   = (float*)d_out;

  prep_kernel<<<24, 256, 0, stream>>>(Wq, Wk, Wv, whi, wlo);
  dim3 g1((n + 127) / 128, 3);
  qkv_kernel<<<g1, 256, 0, stream>>>(h, bq, bk, bv, whi, wlo, qs, ks, vs, n);
  attn_kernel<<<(n + 3) / 4, 256, 0, stream>>>(col_ind, qs, ks, vs, outf, n);
}

// Round 6
// 203.706 us; speedup vs baseline: 1.1863x; 1.0657x over previous
//
#include <hip/hip_runtime.h>
#include <hip/hip_bf16.h>

// SparseMHA, fixed out-degree CSR graph attention. fp32 in/out.
// r5 -> r6: qkv was latency-bound (all pipes <13%): 64 scattered 2B stores per
// wave caused L2 partial-line RMW (WRITE 45MB vs 38.4 ideal, FETCH +13MB).
// Epilogue now repacks C-fragments through per-wave-private LDS (stride 132
// ushorts = conflict-free b16 writes) and stores coalesced 8B/lane rows.
// attn: 2 rows per wave -> 2x outstanding gathers (memory-level parallelism).

typedef unsigned short ushort_t;
typedef unsigned int uint32;
typedef short short8 __attribute__((ext_vector_type(8)));
typedef short short4v __attribute__((ext_vector_type(4)));
typedef float f32x4 __attribute__((ext_vector_type(4)));

#define HID 128
#define DEG 16
#define OSTRIDE_LDS 132   // ushort row stride in LDS repack (bank-conflict-free)

__device__ __forceinline__ float bf2f(ushort_t u) {
  uint32 x = ((uint32)u) << 16;
  return __builtin_bit_cast(float, x);
}
__device__ __forceinline__ ushort_t f2bf(float f) {
  uint32 u = __builtin_bit_cast(uint32, f);
  u += 0x7fffu + ((u >> 16) & 1u);   // RNE
  return (ushort_t)(u >> 16);
}

// Packed split of 2 fp32 -> packed bf16 hi pair + lo pair (RNE, v_cvt_pk path).
__device__ __forceinline__ void split2(float x, float y, uint32& hi, uint32& lo) {
  __hip_bfloat162 h2 = __float22bfloat162_rn(float2{x, y});
  __builtin_memcpy(&hi, &h2, 4);
  float hx = __builtin_bit_cast(float, hi << 16);
  float hy = __builtin_bit_cast(float, hi & 0xffff0000u);
  __hip_bfloat162 l2 = __float22bfloat162_rn(float2{x - hx, y - hy});
  __builtin_memcpy(&lo, &l2, 4);
}

// 8 consecutive fp32 (32B-aligned) -> short8 hi + short8 lo.
__device__ __forceinline__ void split8p(const float* __restrict__ p, short8& hi, short8& lo) {
  float4 a = *(const float4*)p;
  float4 b = *(const float4*)(p + 4);
  uint32* hu = (uint32*)&hi;
  uint32* lu = (uint32*)&lo;
  split2(a.x, a.y, hu[0], lu[0]);
  split2(a.z, a.w, hu[1], lu[1]);
  split2(b.x, b.y, hu[2], lu[2]);
  split2(b.z, b.w, hu[3], lu[3]);
}

// ---------------- Phase 0: pre-split Wq|Wk|Wv into bf16 hi/lo ----------------
__global__ __launch_bounds__(256) void prep_kernel(
    const float* __restrict__ Wq, const float* __restrict__ Wk,
    const float* __restrict__ Wv,
    ushort_t* __restrict__ whi, ushort_t* __restrict__ wlo) {
  const int idx8 = (blockIdx.x * 256 + threadIdx.x) * 8;   // [0, 49152)
  const float* W = (idx8 < 16384) ? Wq : (idx8 < 32768) ? Wk : Wv;
  const int off = idx8 & 16383;
  short8 hi, lo;
  split8p(W + off, hi, lo);
  *(short8*)(whi + idx8) = hi;
  *(short8*)(wlo + idx8) = lo;
}

// ---------------- Phase 1: Q/K/V projection GEMMs ----------------
// out[i,c] = sum_k h[i,k]*W[c,k] + b[c]; q scaled by 0.25 after bias.
// Grid (ceil(n/128), 3); block 256 = 4 waves; wave computes 32 rows x 128 cols.
// Epilogue: fragments -> LDS (per-wave private) -> coalesced 8B/lane stores.
__global__ __launch_bounds__(256) void qkv_kernel(
    const float* __restrict__ h,
    const float* __restrict__ bq, const float* __restrict__ bk,
    const float* __restrict__ bv,
    const ushort_t* __restrict__ whi, const ushort_t* __restrict__ wlo,
    ushort_t* __restrict__ qs, ushort_t* __restrict__ ks, ushort_t* __restrict__ vs,
    int n) {
  __shared__ ushort_t lds_o[4][32 * OSTRIDE_LDS];  // 33 KB

  const int which = blockIdx.y;
  const float* __restrict__ bias = (which == 0) ? bq : (which == 1) ? bk : bv;
  ushort_t* __restrict__ outp = (which == 0) ? qs : (which == 1) ? ks : vs;
  const int ostride = (which == 0) ? 256 : 128;  // q rows live inside 512B fp32 out rows
  const float scale = (which == 0) ? 0.25f : 1.0f;
  const ushort_t* __restrict__ Wh = whi + which * 16384;
  const ushort_t* __restrict__ Wl = wlo + which * 16384;

  const int wave = threadIdx.x >> 6;
  const int l = threadIdx.x & 63;
  const int lm = l & 15;
  const int lq = l >> 4;
  const int m0 = blockIdx.x * 128 + wave * 32;

  int ar0 = m0 + lm;        if (ar0 >= n) ar0 = n - 1;
  int ar1 = m0 + 16 + lm;   if (ar1 >= n) ar1 = n - 1;
  const float* ap0 = h + (size_t)ar0 * HID + lq * 8;
  const float* ap1 = h + (size_t)ar1 * HID + lq * 8;

  f32x4 acc[2][8];
#pragma unroll
  for (int f = 0; f < 2; f++)
#pragma unroll
    for (int t = 0; t < 8; t++) acc[f][t] = (f32x4){0.f, 0.f, 0.f, 0.f};

#pragma unroll
  for (int kt = 0; kt < 4; kt++) {
    short8 ah0, al0, ah1, al1;
    split8p(ap0 + kt * 32, ah0, al0);
    split8p(ap1 + kt * 32, ah1, al1);
    const int boff = kt * 32 + lq * 8 + lm * HID;
#pragma unroll
    for (int t = 0; t < 8; t++) {
      short8 bh = *(const short8*)(Wh + t * 16 * HID + boff);
      short8 bl = *(const short8*)(Wl + t * 16 * HID + boff);
      acc[0][t] = __builtin_amdgcn_mfma_f32_16x16x32_bf16(ah0, bh, acc[0][t], 0, 0, 0);
      acc[0][t] = __builtin_amdgcn_mfma_f32_16x16x32_bf16(ah0, bl, acc[0][t], 0, 0, 0);
      acc[0][t] = __builtin_amdgcn_mfma_f32_16x16x32_bf16(al0, bh, acc[0][t], 0, 0, 0);
      acc[1][t] = __builtin_amdgcn_mfma_f32_16x16x32_bf16(ah1, bh, acc[1][t], 0, 0, 0);
      acc[1][t] = __builtin_amdgcn_mfma_f32_16x16x32_bf16(ah1, bl, acc[1][t], 0, 0, 0);
      acc[1][t] = __builtin_amdgcn_mfma_f32_16x16x32_bf16(al1, bh, acc[1][t], 0, 0, 0);
    }
  }

  // Epilogue A: fragments -> LDS (ushort). D[m][c]: c = lm+16t, m = f*16+lq*4+r.
  // bank = (2m + 8t + lm/2) % 32 per inst -> all 32 banks, 2 lanes each (free).
  ushort_t* lo_ = lds_o[wave];
#pragma unroll
  for (int t = 0; t < 8; t++) {
    const int col = t * 16 + lm;
    const float bv_ = bias[col];
#pragma unroll
    for (int f = 0; f < 2; f++) {
#pragma unroll
      for (int r = 0; r < 4; r++) {
        lo_[(f * 16 + lq * 4 + r) * OSTRIDE_LDS + col] = f2bf((acc[f][t][r] + bv_) * scale);
      }
    }
  }
  // Wave-local LDS ordering (region private to this wave).
  asm volatile("s_waitcnt lgkmcnt(0)" ::: "memory");
  __builtin_amdgcn_wave_barrier();

  // Epilogue B: coalesced writeout. Lane covers an 8B chunk of a row; 32 lanes
  // cover one 256B row contiguously -> 2 full rows per store inst.
  const int rr = l >> 5;          // 0..1
  const int ch = l & 31;          // 8B chunk index
#pragma unroll
  for (int it = 0; it < 16; it++) {
    const int rw = it * 2 + rr;   // row within wave, 0..31
    const int grow = m0 + rw;
    short4v val = *(short4v*)(lo_ + rw * OSTRIDE_LDS + ch * 4);
    if (grow < n) *(short4v*)(outp + (size_t)grow * ostride + ch * 4) = val;
  }
}

// ---------------- Phase 2: fused scores + softmax + aggregate ----------------
// 2 rows per wave (8 per block) for doubled memory-level parallelism.
// Scores via MFMA (gathered K rows as A, diagonal-expanded q as B); V
// prefetched before softmax; per-wave-private LDS, wave-local ordering.
__global__ __launch_bounds__(256) void attn_kernel(
    const int* __restrict__ col_ind,
    const ushort_t* __restrict__ qs, const ushort_t* __restrict__ ks,
    const ushort_t* __restrict__ vs, float* __restrict__ out, int n) {
  __shared__ __align__(16) float lds_attn[4][2 * DEG * 8];  // 4 KB

  const int wv = threadIdx.x >> 6;
  const int l = threadIdx.x & 63;
  const int lm = l & 15;
  const int lq = l >> 4;

  const int row0 = blockIdx.x * 8 + wv * 2;
  int rowi[2];
  rowi[0] = (row0 < n) ? row0 : n - 1;
  rowi[1] = (row0 + 1 < n) ? row0 + 1 : n - 1;

  short8 af[2][4];
  ushort_t qv[2][4];
  uint32 vreg[2][DEG];

#pragma unroll
  for (int rr = 0; rr < 2; rr++) {
    const int eb = rowi[rr] * DEG;
    const int cm = col_ind[eb + lm];
    const ushort_t* kp = ks + (size_t)cm * HID + lq * 8;
    const ushort_t* qp = qs + (size_t)rowi[rr] * 256;   // q embedded in out row
#pragma unroll
    for (int kt = 0; kt < 4; kt++) {
      af[rr][kt] = *(const short8*)(kp + kt * 32);
      qv[rr][kt] = (lm < 8) ? qp[kt * 32 + lq * 8 + lm] : (ushort_t)0;
    }
#pragma unroll
    for (int e = 0; e < DEG; e++) {
      const int c = col_ind[eb + e];                    // wave-uniform -> s_load
      vreg[rr][e] = *(const uint32*)(vs + (size_t)c * HID + 2 * l);
    }
  }

  f32x4 acc[2] = {(f32x4){0.f, 0.f, 0.f, 0.f}, (f32x4){0.f, 0.f, 0.f, 0.f}};
#pragma unroll
  for (int rr = 0; rr < 2; rr++) {
#pragma unroll
    for (int kt = 0; kt < 4; kt++) {
      short8 bf;
#pragma unroll
      for (int j = 0; j < 8; j++) bf[j] = (lm == j) ? (short)qv[rr][kt] : (short)0;
      acc[rr] = __builtin_amdgcn_mfma_f32_16x16x32_bf16(af[rr][kt], bf, acc[rr], 0, 0, 0);
    }
  }
  // acc[rr][r] = score[edge = lq*4 + r][head = lm]   (lm < 8 valid)

#pragma unroll
  for (int rr = 0; rr < 2; rr++) {
    float m = fmaxf(fmaxf(acc[rr][0], acc[rr][1]), fmaxf(acc[rr][2], acc[rr][3]));
    m = fmaxf(m, __shfl_xor(m, 16, 64));
    m = fmaxf(m, __shfl_xor(m, 32, 64));
    float e0 = __expf(acc[rr][0] - m), e1 = __expf(acc[rr][1] - m);
    float e2 = __expf(acc[rr][2] - m), e3 = __expf(acc[rr][3] - m);
    float s = e0 + e1 + e2 + e3;
    s += __shfl_xor(s, 16, 64);
    s += __shfl_xor(s, 32, 64);
    const float inv = 1.0f / s;
    if (lm < 8) {
      float* ap = &lds_attn[wv][rr * DEG * 8];
      ap[(lq * 4 + 0) * 8 + lm] = e0 * inv;
      ap[(lq * 4 + 1) * 8 + lm] = e1 * inv;
      ap[(lq * 4 + 2) * 8 + lm] = e2 * inv;
      ap[(lq * 4 + 3) * 8 + lm] = e3 * inv;
    }
  }
  // Wave-local LDS ordering (region private to this wave).
  asm volatile("s_waitcnt lgkmcnt(0)" ::: "memory");
  __builtin_amdgcn_wave_barrier();

  const int h0 = 2 * (l & 3);
#pragma unroll
  for (int rr = 0; rr < 2; rr++) {
    const float* ap = &lds_attn[wv][rr * DEG * 8];
    float o0 = 0.f, o1 = 0.f;
#pragma unroll
    for (int e = 0; e < DEG; e++) {
      const float2 at = *(const float2*)(ap + e * 8 + h0);
      o0 += at.x * bf2f((ushort_t)(vreg[rr][e] & 0xffffu));
      o1 += at.y * bf2f((ushort_t)(vreg[rr][e] >> 16));
    }
    float2 o = {o0, o1};
    *(float2*)(out + (size_t)rowi[rr] * HID + 2 * l) = o;  // overwrites consumed q
  }
}

extern "C" void kernel_launch(void* const* d_in, const int* in_sizes, int n_in,
                              void* d_out, int out_size, void* d_ws, size_t ws_size,
                              hipStream_t stream) {
  const float* h  = (const float*)d_in[0];
  const float* Wq = (const float*)d_in[1];
  const float* bq = (const float*)d_in[2];
  const float* Wk = (const float*)d_in[3];
  const float* bk = (const float*)d_in[4];
  const float* Wv = (const float*)d_in[5];
  const float* bv = (const float*)d_in[6];
  // d_in[7] = row_ptr (fixed degree 16) — unused
  const int* col_ind = (const int*)d_in[8];
  // d_in[9] = num_heads (= 8) — hardcoded in layout math

  const int n = in_sizes[0] / HID;  // 50000

  // ws layout (~25.8 MB): k, v bf16 tables + W hi/lo splits. q (bf16) lives in
  // the first 256 B of each row's 512 B fp32 out slot.
  ushort_t* ks  = (ushort_t*)d_ws;
  ushort_t* vs  = ks + (size_t)n * HID;
  ushort_t* whi = vs + (size_t)n * HID;
  ushort_t* wlo = whi + 3 * 16384;
  ushort_t* qs  = (ushort_t*)d_out;
  float* outf   = (float*)d_out;

  prep_kernel<<<24, 256, 0, stream>>>(Wq, Wk, Wv, whi, wlo);
  dim3 g1((n + 127) / 128, 3);
  qkv_kernel<<<g1, 256, 0, stream>>>(h, bq, bk, bv, whi, wlo, qs, ks, vs, n);
  attn_kernel<<<(n + 7) / 8, 256, 0, stream>>>(col_ind, qs, ks, vs, outf, n);
}